// Round 2
// baseline (3083.825 us; speedup 1.0000x reference)
//
#include <hip/hip_runtime.h>
#include <cstdint>
#include <cstddef>
#include <cmath>

#define F_IN 256
#define HDIM 128
#define CCLS 40
#define NBMAX 1024   // max buckets (n<=65536); n=50000 -> 782

// ---------------- row L2 norm: one wave per row ----------------
__global__ __launch_bounds__(256) void norm_kernel(const float* __restrict__ x,
                                                   float* __restrict__ inv_norm, int n) {
  int wv = threadIdx.x >> 6, l = threadIdx.x & 63;
  int row = blockIdx.x * 4 + wv;
  if (row >= n) return;
  float4 v = *(const float4*)(x + (size_t)row * F_IN + l * 4);
  float s = v.x * v.x + v.y * v.y + v.z * v.z + v.w * v.w;
#pragma unroll
  for (int off = 32; off; off >>= 1) s += __shfl_xor(s, off, 64);
  if (l == 0) inv_norm[row] = 1.0f / fmaxf(sqrtf(s), 1e-12f);
}

// ---------------- bucket histogram (bucket = dst>>6) ----------------
__global__ __launch_bounds__(256) void bucket_hist(const int* __restrict__ dst,
                                                   int* __restrict__ gcount, int e, int nb) {
  __shared__ int h[NBMAX];
  for (int i = threadIdx.x; i < nb; i += 256) h[i] = 0;
  __syncthreads();
  int base = blockIdx.x * 4096;
#pragma unroll
  for (int k = 0; k < 16; ++k) {
    int i = base + k * 256 + threadIdx.x;
    if (i < e) atomicAdd(&h[dst[i] >> 6], 1);
  }
  __syncthreads();
  for (int i = threadIdx.x; i < nb; i += 256)
    if (h[i]) atomicAdd(&gcount[i], h[i]);
}

// ---------------- exclusive scan of bucket counts (1 block) ----------------
__global__ __launch_bounds__(256) void bucket_scan(const int* __restrict__ gcount,
                                                   int* __restrict__ boff,
                                                   int* __restrict__ gcursor, int nb) {
  __shared__ int part[256];
  int t = threadIdx.x;
  int v[4];
  int s = 0;
#pragma unroll
  for (int k = 0; k < 4; ++k) {
    int i = t * 4 + k;
    v[k] = (i < nb) ? gcount[i] : 0;
    s += v[k];
  }
  part[t] = s;
  __syncthreads();
  for (int off = 1; off < 256; off <<= 1) {
    int x = part[t];
    if (t >= off) x += part[t - off];
    __syncthreads();
    part[t] = x;
    __syncthreads();
  }
  int run = (t == 0) ? 0 : part[t - 1];
#pragma unroll
  for (int k = 0; k < 4; ++k) {
    int i = t * 4 + k;
    if (i < nb) { boff[i] = run; gcursor[i] = run; }
    run += v[k];
  }
  if (t == 255) boff[nb] = part[255];
}

// ---------------- block-multisplit scatter into bucket-grouped edge list ----------------
// edge record: meta = (dst&63)<<26 | src ; w as bits
#define EPB 8192
__global__ __launch_bounds__(256) void bucket_scatter(const int* __restrict__ src,
                                                      const int* __restrict__ dst,
                                                      const float* __restrict__ w,
                                                      int* __restrict__ gcursor,
                                                      uint2* __restrict__ ews, int e, int nb) {
  __shared__ int hist[NBMAX];
  __shared__ int gbase[NBMAX];
  __shared__ int lcur[NBMAX];
  const int t = threadIdx.x;
  for (int i = t; i < nb; i += 256) { hist[i] = 0; lcur[i] = 0; }
  __syncthreads();
  const int base = blockIdx.x * EPB;
  int dv[32];
#pragma unroll
  for (int k = 0; k < 32; ++k) {
    int i = base + k * 256 + t;
    dv[k] = (i < e) ? dst[i] : -1;
    if (dv[k] >= 0) atomicAdd(&hist[dv[k] >> 6], 1);
  }
  __syncthreads();
  for (int i = t; i < nb; i += 256) {
    int c = hist[i];
    gbase[i] = c ? atomicAdd(&gcursor[i], c) : 0;
  }
  __syncthreads();
#pragma unroll
  for (int k = 0; k < 32; ++k) {
    int i = base + k * 256 + t;
    if (i < e) {
      int d = dv[k], b = d >> 6;
      int r = atomicAdd(&lcur[b], 1);
      unsigned meta = ((unsigned)(d & 63) << 26) | (unsigned)src[i];
      ews[gbase[b] + r] = make_uint2(meta, __float_as_uint(w[i]));
    }
  }
}

// ---------------- bucketed SPMM: block = bucket of 64 dst rows, LDS fp32 accumulate ----------------
__global__ __launch_bounds__(256) void spmm_bucket(const float* __restrict__ xin,
                                                   const uint2* __restrict__ ews,
                                                   const int* __restrict__ boff,
                                                   const float* __restrict__ bias,
                                                   float* __restrict__ outp, int n,
                                                   int do_relu) {
  __shared__ float acc[64][128];
  const int t = threadIdx.x;
  const int f = t & 127, g = t >> 7;  // g in {0,1}: which edge of the pair
  for (int i = t; i < 64 * 128; i += 256) ((float*)acc)[i] = 0.f;
  const int b = blockIdx.x;
  const int e0 = boff[b], e1 = boff[b + 1];
  __syncthreads();
  for (int eb = e0; eb < e1; eb += 8) {
    int ee = eb + g * 4;
    uint2 p0, p1, p2, p3;
    float x0 = 0.f, x1 = 0.f, x2 = 0.f, x3 = 0.f;
    bool q0 = ee < e1, q1 = ee + 1 < e1, q2 = ee + 2 < e1, q3 = ee + 3 < e1;
    if (q0) p0 = ews[ee];
    if (q1) p1 = ews[ee + 1];
    if (q2) p2 = ews[ee + 2];
    if (q3) p3 = ews[ee + 3];
    if (q0) x0 = xin[(size_t)(p0.x & 0x3FFFFFFu) * HDIM + f];
    if (q1) x1 = xin[(size_t)(p1.x & 0x3FFFFFFu) * HDIM + f];
    if (q2) x2 = xin[(size_t)(p2.x & 0x3FFFFFFu) * HDIM + f];
    if (q3) x3 = xin[(size_t)(p3.x & 0x3FFFFFFu) * HDIM + f];
    if (q0) atomicAdd(&acc[p0.x >> 26][f], __uint_as_float(p0.y) * x0);
    if (q1) atomicAdd(&acc[p1.x >> 26][f], __uint_as_float(p1.y) * x1);
    if (q2) atomicAdd(&acc[p2.x >> 26][f], __uint_as_float(p2.y) * x2);
    if (q3) atomicAdd(&acc[p3.x >> 26][f], __uint_as_float(p3.y) * x3);
  }
  __syncthreads();
  const float bv = bias[f];
  const int row0 = b * 64;
  for (int i = t; i < 64 * 128; i += 256) {
    int r = i >> 7;
    int gr = row0 + r;
    if (gr < n) {
      float v = acc[r][f] + bv;
      if (do_relu) v = fmaxf(v, 0.f);
      outp[(size_t)gr * HDIM + f] = v;
    }
  }
}

// ---------------- fp32 tiled GEMM: C[M][128] = (scale.A)[M][K] @ W[K][128] ----------------
template <int K, bool SCALE>
__global__ __launch_bounds__(256) void gemm_kernel(const float* __restrict__ A,
                                                   const float* __restrict__ W,
                                                   const float* __restrict__ scale,
                                                   float* __restrict__ C, int M) {
  __shared__ float As[64][33];
  __shared__ float Bs[32][128];
  const int t = threadIdx.x;
  const int tx = t & 15, ty = t >> 4;
  const int m0 = blockIdx.x * 64;
  float acc[4][8];
#pragma unroll
  for (int r = 0; r < 4; ++r)
#pragma unroll
    for (int c = 0; c < 8; ++c) acc[r][c] = 0.f;

  for (int k0 = 0; k0 < K; k0 += 32) {
#pragma unroll
    for (int j = 0; j < 2; ++j) {
      int i = t + j * 256;
      int row = i >> 3, q = i & 7;
      int gr = m0 + row;
      float4 v = make_float4(0.f, 0.f, 0.f, 0.f);
      if (gr < M) {
        v = *(const float4*)(A + (size_t)gr * K + k0 + q * 4);
        if (SCALE) {
          float sc = scale[gr];
          v.x *= sc; v.y *= sc; v.z *= sc; v.w *= sc;
        }
      }
      As[row][q * 4 + 0] = v.x;
      As[row][q * 4 + 1] = v.y;
      As[row][q * 4 + 2] = v.z;
      As[row][q * 4 + 3] = v.w;
    }
#pragma unroll
    for (int j = 0; j < 4; ++j) {
      int i = t + j * 256;
      int kr = i >> 5, n4 = i & 31;
      *(float4*)&Bs[kr][n4 * 4] = *(const float4*)(W + (size_t)(k0 + kr) * HDIM + n4 * 4);
    }
    __syncthreads();
#pragma unroll
    for (int kr = 0; kr < 32; ++kr) {
      float a[4];
#pragma unroll
      for (int r = 0; r < 4; ++r) a[r] = As[ty * 4 + r][kr];
      float4 b0 = *(const float4*)&Bs[kr][tx * 8];
      float4 b1 = *(const float4*)&Bs[kr][tx * 8 + 4];
      float bb[8] = {b0.x, b0.y, b0.z, b0.w, b1.x, b1.y, b1.z, b1.w};
#pragma unroll
      for (int r = 0; r < 4; ++r)
#pragma unroll
        for (int c = 0; c < 8; ++c) acc[r][c] += a[r] * bb[c];
    }
    __syncthreads();
  }
#pragma unroll
  for (int r = 0; r < 4; ++r) {
    int gr = m0 + ty * 4 + r;
    if (gr < M) {
      float4 o0 = make_float4(acc[r][0], acc[r][1], acc[r][2], acc[r][3]);
      float4 o1 = make_float4(acc[r][4], acc[r][5], acc[r][6], acc[r][7]);
      *(float4*)(C + (size_t)gr * HDIM + tx * 8) = o0;
      *(float4*)(C + (size_t)gr * HDIM + tx * 8 + 4) = o1;
    }
  }
}

// ---------------- fold label-emb weights: Wc = We @ Wf_top, bc = be @ Wf_top + bf ----------------
__global__ __launch_bounds__(256) void wc_kernel(const float* __restrict__ We,
                                                 const float* __restrict__ be,
                                                 const float* __restrict__ Wf,
                                                 const float* __restrict__ bf,
                                                 float* __restrict__ Wc,
                                                 float* __restrict__ bc) {
  int t = threadIdx.x;
  for (int i = t; i < CCLS * CCLS; i += 256) {
    int c = i / CCLS, j = i % CCLS;
    float s = 0.f;
    for (int f = 0; f < HDIM; ++f) s += We[c * HDIM + f] * Wf[f * CCLS + j];
    Wc[i] = s;
  }
  if (t < CCLS) {
    float s = bf[t];
    for (int f = 0; f < HDIM; ++f) s += be[f] * Wf[f * CCLS + t];
    bc[t] = s;
  }
}

// ---------------- head: logits = y@Wc + h2@Wf_bot + bc, softmax ----------------
__global__ __launch_bounds__(256) void head_kernel(const float* __restrict__ y,
                                                   const float* __restrict__ h2,
                                                   const float* __restrict__ Wc,
                                                   const float* __restrict__ bc,
                                                   const float* __restrict__ Wf,
                                                   float* __restrict__ out, int n) {
  __shared__ float sW[168][44];
  __shared__ float zb[4][172];
  const int t = threadIdx.x;
  for (int i = t; i < CCLS * CCLS; i += 256) sW[i / CCLS][i % CCLS] = Wc[i];
  for (int i = t; i < HDIM * CCLS; i += 256) sW[CCLS + i / CCLS][i % CCLS] = Wf[HDIM * CCLS + i];
  __syncthreads();
  const int wv = t >> 6, l = t & 63;
  float bcl = (l < CCLS) ? bc[l] : 0.f;
  float* z = zb[wv];
  for (int it = 0; it < 16; ++it) {
    int node = blockIdx.x * 64 + wv * 16 + it;
    int nc = node < n ? node : n - 1;
    if (l < CCLS) z[l] = y[(size_t)nc * CCLS + l];
    z[40 + l] = h2[(size_t)nc * HDIM + l];
    z[104 + l] = h2[(size_t)nc * HDIM + 64 + l];
    __syncthreads();
    float acc = (l < CCLS) ? bcl : -INFINITY;
#pragma unroll
    for (int k = 0; k < 168; k += 4) {
      float4 zv = *(const float4*)&z[k];
      if (l < CCLS) {
        acc += zv.x * sW[k + 0][l];
        acc += zv.y * sW[k + 1][l];
        acc += zv.z * sW[k + 2][l];
        acc += zv.w * sW[k + 3][l];
      }
    }
    float m = acc;
#pragma unroll
    for (int off = 32; off; off >>= 1) m = fmaxf(m, __shfl_xor(m, off, 64));
    float ev = (l < CCLS) ? __expf(acc - m) : 0.f;
    float sum = ev;
#pragma unroll
    for (int off = 32; off; off >>= 1) sum += __shfl_xor(sum, off, 64);
    if (node < n && l < CCLS) out[(size_t)node * CCLS + l] = ev / sum;
    __syncthreads();
  }
}

extern "C" void kernel_launch(void* const* d_in, const int* in_sizes, int n_in,
                              void* d_out, int out_size, void* d_ws, size_t ws_size,
                              hipStream_t stream) {
  (void)n_in; (void)out_size; (void)ws_size;
  const float* features = (const float*)d_in[0];
  const int*   src      = (const int*)d_in[1];
  const int*   dst      = (const int*)d_in[2];
  const float* ew       = (const float*)d_in[3];
  const float* y        = (const float*)d_in[4];
  const float* W1       = (const float*)d_in[5];
  const float* b1       = (const float*)d_in[6];
  const float* W2       = (const float*)d_in[7];
  const float* b2       = (const float*)d_in[8];
  const float* We       = (const float*)d_in[9];
  const float* be       = (const float*)d_in[10];
  const float* Wf       = (const float*)d_in[11];
  const float* bf       = (const float*)d_in[12];
  float* out = (float*)d_out;

  const int n = in_sizes[0] / F_IN;   // 50000
  const int e = in_sizes[1];          // 1600000
  const int nb = (n + 63) >> 6;       // 782 buckets

  char* w = (char*)d_ws;
  auto take = [&](size_t bytes) {
    char* p = w;
    w += (bytes + 255) & ~(size_t)255;
    return p;
  };
  float* inv_norm = (float*)take((size_t)n * 4);
  int*   gcount   = (int*)take((size_t)nb * 4);
  int*   boff     = (int*)take((size_t)(nb + 1) * 4);
  int*   gcursor  = (int*)take((size_t)nb * 4);
  uint2* ews      = (uint2*)take((size_t)e * 8);
  float* bufA     = (float*)take((size_t)n * HDIM * 4);
  float* bufB     = (float*)take((size_t)n * HDIM * 4);
  float* Wc       = (float*)take(CCLS * CCLS * 4);
  float* bc       = (float*)take(CCLS * 4);

  hipMemsetAsync(gcount, 0, (size_t)nb * 4, stream);
  norm_kernel<<<(n + 3) / 4, 256, 0, stream>>>(features, inv_norm, n);
  bucket_hist<<<(e + 4095) / 4096, 256, 0, stream>>>(dst, gcount, e, nb);
  bucket_scan<<<1, 256, 0, stream>>>(gcount, boff, gcursor, nb);
  bucket_scatter<<<(e + EPB - 1) / EPB, 256, 0, stream>>>(src, dst, ew, gcursor, ews, e, nb);
  wc_kernel<<<1, 256, 0, stream>>>(We, be, Wf, bf, Wc, bc);

  gemm_kernel<F_IN, true><<<(n + 63) / 64, 256, 0, stream>>>(features, W1, inv_norm, bufA, n);
  spmm_bucket<<<nb, 256, 0, stream>>>(bufA, ews, boff, b1, bufB, n, 1);
  gemm_kernel<HDIM, false><<<(n + 63) / 64, 256, 0, stream>>>(bufB, W2, nullptr, bufA, n);
  spmm_bucket<<<nb, 256, 0, stream>>>(bufA, ews, boff, b2, bufB, n, 0);
  head_kernel<<<(n + 63) / 64, 256, 0, stream>>>(y, bufB, Wc, bc, Wf, out, n);
}

// Round 3
// 608.153 us; speedup vs baseline: 5.0708x; 5.0708x over previous
//
#include <hip/hip_runtime.h>
#include <cstdint>
#include <cstddef>
#include <cmath>

#define F_IN 256
#define HDIM 128
#define CCLS 40
#define NBMAX 1024   // max buckets (n<=65536); n=50000 -> 782

// ---------------- row L2 norm: one wave per row ----------------
__global__ __launch_bounds__(256) void norm_kernel(const float* __restrict__ x,
                                                   float* __restrict__ inv_norm, int n) {
  int wv = threadIdx.x >> 6, l = threadIdx.x & 63;
  int row = blockIdx.x * 4 + wv;
  if (row >= n) return;
  float4 v = *(const float4*)(x + (size_t)row * F_IN + l * 4);
  float s = v.x * v.x + v.y * v.y + v.z * v.z + v.w * v.w;
#pragma unroll
  for (int off = 32; off; off >>= 1) s += __shfl_xor(s, off, 64);
  if (l == 0) inv_norm[row] = 1.0f / fmaxf(sqrtf(s), 1e-12f);
}

// ---------------- bucket histogram (bucket = dst>>6) ----------------
__global__ __launch_bounds__(256) void bucket_hist(const int* __restrict__ dst,
                                                   int* __restrict__ gcount, int e, int nb) {
  __shared__ int h[NBMAX];
  for (int i = threadIdx.x; i < nb; i += 256) h[i] = 0;
  __syncthreads();
  int base = blockIdx.x * 4096;
#pragma unroll
  for (int k = 0; k < 16; ++k) {
    int i = base + k * 256 + threadIdx.x;
    if (i < e) atomicAdd(&h[dst[i] >> 6], 1);
  }
  __syncthreads();
  for (int i = threadIdx.x; i < nb; i += 256)
    if (h[i]) atomicAdd(&gcount[i], h[i]);
}

// ---------------- exclusive scan of bucket counts (1 block) ----------------
__global__ __launch_bounds__(256) void bucket_scan(const int* __restrict__ gcount,
                                                   int* __restrict__ boff,
                                                   int* __restrict__ gcursor,
                                                   int* __restrict__ row_off,
                                                   int nb, int n) {
  __shared__ int part[256];
  int t = threadIdx.x;
  int v[4];
  int s = 0;
#pragma unroll
  for (int k = 0; k < 4; ++k) {
    int i = t * 4 + k;
    v[k] = (i < nb) ? gcount[i] : 0;
    s += v[k];
  }
  part[t] = s;
  __syncthreads();
  for (int off = 1; off < 256; off <<= 1) {
    int x = part[t];
    if (t >= off) x += part[t - off];
    __syncthreads();
    part[t] = x;
    __syncthreads();
  }
  int run = (t == 0) ? 0 : part[t - 1];
#pragma unroll
  for (int k = 0; k < 4; ++k) {
    int i = t * 4 + k;
    if (i < nb) { boff[i] = run; gcursor[i] = run; }
    run += v[k];
  }
  if (t == 255) { boff[nb] = part[255]; row_off[n] = part[255]; }
}

// ---------------- block-multisplit scatter into bucket-grouped edge list ----------------
// edge record: meta = (dst&63)<<26 | src ; w as bits
#define EPB 8192
__global__ __launch_bounds__(256) void bucket_scatter(const int* __restrict__ src,
                                                      const int* __restrict__ dst,
                                                      const float* __restrict__ w,
                                                      int* __restrict__ gcursor,
                                                      uint2* __restrict__ ews, int e, int nb) {
  __shared__ int hist[NBMAX];
  __shared__ int gbase[NBMAX];
  __shared__ int lcur[NBMAX];
  const int t = threadIdx.x;
  for (int i = t; i < nb; i += 256) { hist[i] = 0; lcur[i] = 0; }
  __syncthreads();
  const int base = blockIdx.x * EPB;
  int dv[32];
#pragma unroll
  for (int k = 0; k < 32; ++k) {
    int i = base + k * 256 + t;
    dv[k] = (i < e) ? dst[i] : -1;
    if (dv[k] >= 0) atomicAdd(&hist[dv[k] >> 6], 1);
  }
  __syncthreads();
  for (int i = t; i < nb; i += 256) {
    int c = hist[i];
    gbase[i] = c ? atomicAdd(&gcursor[i], c) : 0;
  }
  __syncthreads();
#pragma unroll
  for (int k = 0; k < 32; ++k) {
    int i = base + k * 256 + t;
    if (i < e) {
      int d = dv[k], b = d >> 6;
      int r = atomicAdd(&lcur[b], 1);
      unsigned meta = ((unsigned)(d & 63) << 26) | (unsigned)src[i];
      ews[gbase[b] + r] = make_uint2(meta, __float_as_uint(w[i]));
    }
  }
}

// ---------------- per-bucket dst-sort: bucket-grouped -> dst-sorted CSR ----------------
// One block per bucket. All writes land in a 16KB window -> full line combining in L2.
__global__ __launch_bounds__(256) void bucket_sort(const uint2* __restrict__ ews,
                                                   const int* __restrict__ boff,
                                                   uint2* __restrict__ ews2,
                                                   int* __restrict__ row_off,
                                                   int n) {
  __shared__ int cnt64[64];
  __shared__ int cur[64];
  const int t = threadIdx.x;
  const int b = blockIdx.x;
  const int e0 = boff[b], e1 = boff[b + 1];
  if (t < 64) cnt64[t] = 0;
  __syncthreads();
  for (int i = e0 + t; i < e1; i += 256) atomicAdd(&cnt64[(unsigned)ews[i].x >> 26], 1);
  __syncthreads();
  if (t == 0) {  // serial exclusive scan of 64 — trivial
    int run = 0;
    for (int d = 0; d < 64; ++d) {
      int c = cnt64[d];
      cur[d] = run;
      run += c;
    }
  }
  __syncthreads();
  if (t < 64) {
    int node = b * 64 + t;
    if (node < n) row_off[node] = e0 + cur[t];
  }
  __syncthreads();
  for (int i = e0 + t; i < e1; i += 256) {
    uint2 p = ews[i];
    int d = (unsigned)p.x >> 26;
    int pos = e0 + atomicAdd(&cur[d], 1);
    ews2[pos] = make_uint2(p.x & 0x3FFFFFFu, p.y);
  }
}

// ---------------- SPMM (dst-sorted CSR): regs accumulate, shfl-broadcast edges ----------------
__global__ __launch_bounds__(256) void spmm_csr(const float* __restrict__ xin,
                                                const uint2* __restrict__ ews,
                                                const int* __restrict__ row_off,
                                                const float* __restrict__ bias,
                                                float* __restrict__ outp, int n,
                                                int do_relu) {
  const int t = threadIdx.x;
  const int l = t & 63;
  const int w = t >> 6;                       // 4 waves
  const int node = blockIdx.x * 2 + (w >> 1); // 2 nodes/block
  const int f = (w & 1) * 64 + l;
  if (node >= n) return;
  const int e0 = row_off[node], e1 = row_off[node + 1];
  float acc = 0.f;
  for (int base = e0; base < e1; base += 64) {
    const int cnt = min(64, e1 - base);
    uint2 ed = make_uint2(0u, 0u);
    if (base + l < e1) ed = ews[base + l];   // coalesced edge-record load into regs
    int k = 0;
    for (; k + 8 <= cnt; k += 8) {
      unsigned s0 = __shfl(ed.x, k + 0), w0 = __shfl(ed.y, k + 0);
      unsigned s1 = __shfl(ed.x, k + 1), w1 = __shfl(ed.y, k + 1);
      unsigned s2 = __shfl(ed.x, k + 2), w2 = __shfl(ed.y, k + 2);
      unsigned s3 = __shfl(ed.x, k + 3), w3 = __shfl(ed.y, k + 3);
      unsigned s4 = __shfl(ed.x, k + 4), w4 = __shfl(ed.y, k + 4);
      unsigned s5 = __shfl(ed.x, k + 5), w5 = __shfl(ed.y, k + 5);
      unsigned s6 = __shfl(ed.x, k + 6), w6 = __shfl(ed.y, k + 6);
      unsigned s7 = __shfl(ed.x, k + 7), w7 = __shfl(ed.y, k + 7);
      float x0 = xin[(size_t)s0 * HDIM + f];
      float x1 = xin[(size_t)s1 * HDIM + f];
      float x2 = xin[(size_t)s2 * HDIM + f];
      float x3 = xin[(size_t)s3 * HDIM + f];
      float x4 = xin[(size_t)s4 * HDIM + f];
      float x5 = xin[(size_t)s5 * HDIM + f];
      float x6 = xin[(size_t)s6 * HDIM + f];
      float x7 = xin[(size_t)s7 * HDIM + f];
      acc = fmaf(__uint_as_float(w0), x0, acc);
      acc = fmaf(__uint_as_float(w1), x1, acc);
      acc = fmaf(__uint_as_float(w2), x2, acc);
      acc = fmaf(__uint_as_float(w3), x3, acc);
      acc = fmaf(__uint_as_float(w4), x4, acc);
      acc = fmaf(__uint_as_float(w5), x5, acc);
      acc = fmaf(__uint_as_float(w6), x6, acc);
      acc = fmaf(__uint_as_float(w7), x7, acc);
    }
    for (; k < cnt; ++k) {
      unsigned s0 = __shfl(ed.x, k), w0 = __shfl(ed.y, k);
      acc = fmaf(__uint_as_float(w0), xin[(size_t)s0 * HDIM + f], acc);
    }
  }
  acc += bias[f];
  if (do_relu) acc = fmaxf(acc, 0.f);
  outp[(size_t)node * HDIM + f] = acc;
}

// ---------------- fp32 tiled GEMM: C[M][128] = (scale.A)[M][K] @ W[K][128] ----------------
template <int K, bool SCALE>
__global__ __launch_bounds__(256) void gemm_kernel(const float* __restrict__ A,
                                                   const float* __restrict__ W,
                                                   const float* __restrict__ scale,
                                                   float* __restrict__ C, int M) {
  __shared__ float As[64][33];
  __shared__ float Bs[32][128];
  const int t = threadIdx.x;
  const int tx = t & 15, ty = t >> 4;
  const int m0 = blockIdx.x * 64;
  float acc[4][8];
#pragma unroll
  for (int r = 0; r < 4; ++r)
#pragma unroll
    for (int c = 0; c < 8; ++c) acc[r][c] = 0.f;

  for (int k0 = 0; k0 < K; k0 += 32) {
#pragma unroll
    for (int j = 0; j < 2; ++j) {
      int i = t + j * 256;
      int row = i >> 3, q = i & 7;
      int gr = m0 + row;
      float4 v = make_float4(0.f, 0.f, 0.f, 0.f);
      if (gr < M) {
        v = *(const float4*)(A + (size_t)gr * K + k0 + q * 4);
        if (SCALE) {
          float sc = scale[gr];
          v.x *= sc; v.y *= sc; v.z *= sc; v.w *= sc;
        }
      }
      As[row][q * 4 + 0] = v.x;
      As[row][q * 4 + 1] = v.y;
      As[row][q * 4 + 2] = v.z;
      As[row][q * 4 + 3] = v.w;
    }
#pragma unroll
    for (int j = 0; j < 4; ++j) {
      int i = t + j * 256;
      int kr = i >> 5, n4 = i & 31;
      *(float4*)&Bs[kr][n4 * 4] = *(const float4*)(W + (size_t)(k0 + kr) * HDIM + n4 * 4);
    }
    __syncthreads();
#pragma unroll
    for (int kr = 0; kr < 32; ++kr) {
      float a[4];
#pragma unroll
      for (int r = 0; r < 4; ++r) a[r] = As[ty * 4 + r][kr];
      float4 b0 = *(const float4*)&Bs[kr][tx * 8];
      float4 b1 = *(const float4*)&Bs[kr][tx * 8 + 4];
      float bb[8] = {b0.x, b0.y, b0.z, b0.w, b1.x, b1.y, b1.z, b1.w};
#pragma unroll
      for (int r = 0; r < 4; ++r)
#pragma unroll
        for (int c = 0; c < 8; ++c) acc[r][c] += a[r] * bb[c];
    }
    __syncthreads();
  }
#pragma unroll
  for (int r = 0; r < 4; ++r) {
    int gr = m0 + ty * 4 + r;
    if (gr < M) {
      float4 o0 = make_float4(acc[r][0], acc[r][1], acc[r][2], acc[r][3]);
      float4 o1 = make_float4(acc[r][4], acc[r][5], acc[r][6], acc[r][7]);
      *(float4*)(C + (size_t)gr * HDIM + tx * 8) = o0;
      *(float4*)(C + (size_t)gr * HDIM + tx * 8 + 4) = o1;
    }
  }
}

// ---------------- fold label-emb weights: Wc = We @ Wf_top, bc = be @ Wf_top + bf ----------------
__global__ __launch_bounds__(256) void wc_kernel(const float* __restrict__ We,
                                                 const float* __restrict__ be,
                                                 const float* __restrict__ Wf,
                                                 const float* __restrict__ bf,
                                                 float* __restrict__ Wc,
                                                 float* __restrict__ bc) {
  int t = threadIdx.x;
  for (int i = t; i < CCLS * CCLS; i += 256) {
    int c = i / CCLS, j = i % CCLS;
    float s = 0.f;
    for (int f = 0; f < HDIM; ++f) s += We[c * HDIM + f] * Wf[f * CCLS + j];
    Wc[i] = s;
  }
  if (t < CCLS) {
    float s = bf[t];
    for (int f = 0; f < HDIM; ++f) s += be[f] * Wf[f * CCLS + t];
    bc[t] = s;
  }
}

// ---------------- head: logits = y@Wc + h2@Wf_bot + bc, softmax ----------------
__global__ __launch_bounds__(256) void head_kernel(const float* __restrict__ y,
                                                   const float* __restrict__ h2,
                                                   const float* __restrict__ Wc,
                                                   const float* __restrict__ bc,
                                                   const float* __restrict__ Wf,
                                                   float* __restrict__ out, int n) {
  __shared__ float sW[168][44];
  __shared__ float zb[4][172];
  const int t = threadIdx.x;
  for (int i = t; i < CCLS * CCLS; i += 256) sW[i / CCLS][i % CCLS] = Wc[i];
  for (int i = t; i < HDIM * CCLS; i += 256) sW[CCLS + i / CCLS][i % CCLS] = Wf[HDIM * CCLS + i];
  __syncthreads();
  const int wv = t >> 6, l = t & 63;
  float bcl = (l < CCLS) ? bc[l] : 0.f;
  float* z = zb[wv];
  for (int it = 0; it < 16; ++it) {
    int node = blockIdx.x * 64 + wv * 16 + it;
    int nc = node < n ? node : n - 1;
    if (l < CCLS) z[l] = y[(size_t)nc * CCLS + l];
    z[40 + l] = h2[(size_t)nc * HDIM + l];
    z[104 + l] = h2[(size_t)nc * HDIM + 64 + l];
    __syncthreads();
    float acc = (l < CCLS) ? bcl : -INFINITY;
#pragma unroll
    for (int k = 0; k < 168; k += 4) {
      float4 zv = *(const float4*)&z[k];
      if (l < CCLS) {
        acc += zv.x * sW[k + 0][l];
        acc += zv.y * sW[k + 1][l];
        acc += zv.z * sW[k + 2][l];
        acc += zv.w * sW[k + 3][l];
      }
    }
    float m = acc;
#pragma unroll
    for (int off = 32; off; off >>= 1) m = fmaxf(m, __shfl_xor(m, off, 64));
    float ev = (l < CCLS) ? __expf(acc - m) : 0.f;
    float sum = ev;
#pragma unroll
    for (int off = 32; off; off >>= 1) sum += __shfl_xor(sum, off, 64);
    if (node < n && l < CCLS) out[(size_t)node * CCLS + l] = ev / sum;
    __syncthreads();
  }
}

extern "C" void kernel_launch(void* const* d_in, const int* in_sizes, int n_in,
                              void* d_out, int out_size, void* d_ws, size_t ws_size,
                              hipStream_t stream) {
  (void)n_in; (void)out_size; (void)ws_size;
  const float* features = (const float*)d_in[0];
  const int*   src      = (const int*)d_in[1];
  const int*   dst      = (const int*)d_in[2];
  const float* ew       = (const float*)d_in[3];
  const float* y        = (const float*)d_in[4];
  const float* W1       = (const float*)d_in[5];
  const float* b1       = (const float*)d_in[6];
  const float* W2       = (const float*)d_in[7];
  const float* b2       = (const float*)d_in[8];
  const float* We       = (const float*)d_in[9];
  const float* be       = (const float*)d_in[10];
  const float* Wf       = (const float*)d_in[11];
  const float* bf       = (const float*)d_in[12];
  float* out = (float*)d_out;

  const int n = in_sizes[0] / F_IN;   // 50000
  const int e = in_sizes[1];          // 1600000
  const int nb = (n + 63) >> 6;       // 782 buckets

  char* w = (char*)d_ws;
  auto take = [&](size_t bytes) {
    char* p = w;
    w += (bytes + 255) & ~(size_t)255;
    return p;
  };
  float* inv_norm = (float*)take((size_t)n * 4);
  int*   gcount   = (int*)take((size_t)nb * 4);
  int*   boff     = (int*)take((size_t)(nb + 1) * 4);
  int*   gcursor  = (int*)take((size_t)nb * 4);
  int*   row_off  = (int*)take((size_t)(n + 1) * 4);
  uint2* ews      = (uint2*)take((size_t)e * 8);
  uint2* ews2     = (uint2*)take((size_t)e * 8);
  float* bufA     = (float*)take((size_t)n * HDIM * 4);
  float* bufB     = (float*)take((size_t)n * HDIM * 4);
  float* Wc       = (float*)take(CCLS * CCLS * 4);
  float* bc       = (float*)take(CCLS * 4);

  hipMemsetAsync(gcount, 0, (size_t)nb * 4, stream);
  norm_kernel<<<(n + 3) / 4, 256, 0, stream>>>(features, inv_norm, n);
  bucket_hist<<<(e + 4095) / 4096, 256, 0, stream>>>(dst, gcount, e, nb);
  bucket_scan<<<1, 256, 0, stream>>>(gcount, boff, gcursor, row_off, nb, n);
  bucket_scatter<<<(e + EPB - 1) / EPB, 256, 0, stream>>>(src, dst, ew, gcursor, ews, e, nb);
  bucket_sort<<<nb, 256, 0, stream>>>(ews, boff, ews2, row_off, n);
  wc_kernel<<<1, 256, 0, stream>>>(We, be, Wf, bf, Wc, bc);

  gemm_kernel<F_IN, true><<<(n + 63) / 64, 256, 0, stream>>>(features, W1, inv_norm, bufA, n);
  spmm_csr<<<(n + 1) / 2, 256, 0, stream>>>(bufA, ews2, row_off, b1, bufB, n, 1);
  gemm_kernel<HDIM, false><<<(n + 63) / 64, 256, 0, stream>>>(bufB, W2, nullptr, bufA, n);
  spmm_csr<<<(n + 1) / 2, 256, 0, stream>>>(bufA, ews2, row_off, b2, bufB, n, 0);
  head_kernel<<<(n + 63) / 64, 256, 0, stream>>>(y, bufB, Wc, bc, Wf, out, n);
}